// Round 1
// baseline (738.987 us; speedup 1.0000x reference)
//
#include <hip/hip_runtime.h>
#include <math.h>

#define DIM   1024
#define NV    512
#define VD    256
#define NTOK  32768

// Output layout (floats): out | soft | perp | gumbel
#define SOFT_OFF  8388608u    // 32768*256
#define PERP_OFF  25165824u   // + 32768*512
#define GUM_OFF   25165825u   // + 1  (odd -> only 4B aligned!)

// ---------------------------------------------------------------------------
// K1: logits = x @ W^T, zero col 0, multiply by mask[token]; write fp32 into
// the soft_probs region of d_out (later overwritten in-place by K2).
// Tiling: 64x64 C-tile, BK=16, 256 threads, 4x4 micro-tile per thread.
// ---------------------------------------------------------------------------
#define BM 64
#define BN 64
#define BK 16
#define PAD 4

__global__ __launch_bounds__(256) void k_gemm(const float* __restrict__ x,
                                              const float* __restrict__ W,
                                              const float* __restrict__ mask,
                                              float* __restrict__ logits) {
    __shared__ float As[BK][BM + PAD];
    __shared__ float Bs[BK][BN + PAD];

    const int tid = threadIdx.x;
    const int n0 = blockIdx.x * BN;
    const int m0 = blockIdx.y * BM;
    const int lr  = tid >> 2;   // 0..63 : row within tile (load phase)
    const int lc4 = tid & 3;    // 0..3  : float4 column within BK
    const int tx = tid & 15;    // compute-phase col group
    const int ty = tid >> 4;    // compute-phase row group

    float c[4][4];
#pragma unroll
    for (int i = 0; i < 4; ++i)
#pragma unroll
        for (int j = 0; j < 4; ++j) c[i][j] = 0.f;

    const float* aptr = x + (size_t)(m0 + lr) * DIM + lc4 * 4;
    const float* bptr = W + (size_t)(n0 + lr) * DIM + lc4 * 4;

    for (int k0 = 0; k0 < DIM; k0 += BK) {
        float4 a = *(const float4*)(aptr + k0);
        float4 b = *(const float4*)(bptr + k0);
        __syncthreads();
        As[lc4 * 4 + 0][lr] = a.x; As[lc4 * 4 + 1][lr] = a.y;
        As[lc4 * 4 + 2][lr] = a.z; As[lc4 * 4 + 3][lr] = a.w;
        Bs[lc4 * 4 + 0][lr] = b.x; Bs[lc4 * 4 + 1][lr] = b.y;
        Bs[lc4 * 4 + 2][lr] = b.z; Bs[lc4 * 4 + 3][lr] = b.w;
        __syncthreads();
#pragma unroll
        for (int k = 0; k < BK; ++k) {
            float4 a4 = *(const float4*)&As[k][ty * 4];
            float4 b4 = *(const float4*)&Bs[k][tx * 4];
            float av[4] = {a4.x, a4.y, a4.z, a4.w};
            float bv[4] = {b4.x, b4.y, b4.z, b4.w};
#pragma unroll
            for (int i = 0; i < 4; ++i)
#pragma unroll
                for (int j = 0; j < 4; ++j) c[i][j] = fmaf(av[i], bv[j], c[i][j]);
        }
    }

#pragma unroll
    for (int i = 0; i < 4; ++i) {
        const int m = m0 + ty * 4 + i;
        const float mk = mask[m];
        const int n = n0 + tx * 4;
        float4 v;
        v.x = (n == 0 ? 0.f : c[i][0]) * mk;
        v.y = c[i][1] * mk;
        v.z = c[i][2] * mk;
        v.w = c[i][3] * mk;
        *(float4*)(logits + (size_t)m * NV + n) = v;
    }
}

// ---------------------------------------------------------------------------
// K2: per-token epilogue. One 64-lane wave per token (4 waves / block).
// Reads the 512 logits (coalesced float4 pairs), argmax with lowest-index
// tie-break, softmax written in-place, one-hot into gumbel region,
// codebook-row gather into out.
// ---------------------------------------------------------------------------
__global__ __launch_bounds__(256) void k_token(float* __restrict__ soft,
                                               float* __restrict__ gumbel,
                                               float* __restrict__ outp,
                                               const float* __restrict__ codebook) {
    const int lane = threadIdx.x & 63;
    const int wave = threadIdx.x >> 6;
    const int t = blockIdx.x * 4 + wave;

    float* row = soft + (size_t)t * NV;
    // lane covers cols lane*4..+3 and 256+lane*4..+3 (fully coalesced)
    float4 u0 = *(const float4*)(row + lane * 4);
    float4 u1 = *(const float4*)(row + 256 + lane * 4);
    float v[8] = {u0.x, u0.y, u0.z, u0.w, u1.x, u1.y, u1.z, u1.w};
    int idx[8];
#pragma unroll
    for (int j = 0; j < 4; ++j) { idx[j] = lane * 4 + j; idx[4 + j] = 256 + lane * 4 + j; }

    // per-lane argmax (strict > keeps lowest index since idx increases)
    float bmax = v[0]; int bidx = idx[0];
#pragma unroll
    for (int j = 1; j < 8; ++j)
        if (v[j] > bmax) { bmax = v[j]; bidx = idx[j]; }
    // wave butterfly reduce: max value, min index on ties
#pragma unroll
    for (int off = 32; off > 0; off >>= 1) {
        float om = __shfl_xor(bmax, off, 64);
        int   oi = __shfl_xor(bidx, off, 64);
        if (om > bmax || (om == bmax && oi < bidx)) { bmax = om; bidx = oi; }
    }
    const float mval = bmax;
    const int k = bidx;

    // softmax
    float e[8]; float s = 0.f;
#pragma unroll
    for (int j = 0; j < 8; ++j) { e[j] = __expf(v[j] - mval); s += e[j]; }
#pragma unroll
    for (int off = 32; off > 0; off >>= 1) s += __shfl_xor(s, off, 64);
    const float inv = 1.f / s;
    float4 w0 = {e[0] * inv, e[1] * inv, e[2] * inv, e[3] * inv};
    float4 w1 = {e[4] * inv, e[5] * inv, e[6] * inv, e[7] * inv};
    *(float4*)(row + lane * 4) = w0;
    *(float4*)(row + 256 + lane * 4) = w1;

    // one-hot into gumbel region (4B-aligned scalar stores, coalesced)
    float* grow = gumbel + (size_t)t * NV;
#pragma unroll
    for (int j = 0; j < 8; ++j) {
        const int col = j * 64 + lane;
        grow[col] = (col == k) ? 1.f : 0.f;
    }

    // out = codebook[k] (row 0 zeroed)
    float4 cbv;
    if (k == 0) {
        cbv.x = cbv.y = cbv.z = cbv.w = 0.f;
    } else {
        cbv = *(const float4*)(codebook + (size_t)k * VD + lane * 4);
    }
    *(float4*)(outp + (size_t)t * VD + lane * 4) = cbv;
}

// ---------------------------------------------------------------------------
// K3: masked column sums of soft_probs -> d_ws[0..512)
// grid (2, 64): blockIdx.x picks 256-column half, blockIdx.y picks 512-row band
// ---------------------------------------------------------------------------
__global__ __launch_bounds__(256) void k_colsum(const float* __restrict__ soft,
                                                const float* __restrict__ mask,
                                                float* __restrict__ sums) {
    const int c = blockIdx.x * 256 + threadIdx.x;
    const int r0 = blockIdx.y * 512;
    float acc = 0.f;
    for (int r = r0; r < r0 + 512; ++r)
        acc = fmaf(soft[(size_t)r * NV + c], mask[r], acc);
    atomicAdd(&sums[c], acc);
}

// ---------------------------------------------------------------------------
// K4: perplexity = exp(-sum(avg*log(avg+eps))), avg = colsum / sum(mask)
// ---------------------------------------------------------------------------
__global__ __launch_bounds__(256) void k_perp(const float* __restrict__ sums,
                                              const float* __restrict__ mask,
                                              float* __restrict__ perp) {
    __shared__ float red[256];
    const int tid = threadIdx.x;
    float ms = 0.f;
    for (int r = tid; r < NTOK; r += 256) ms += mask[r];
    red[tid] = ms;
    __syncthreads();
    for (int s = 128; s > 0; s >>= 1) {
        if (tid < s) red[tid] += red[tid + s];
        __syncthreads();
    }
    const float msum = red[0];
    __syncthreads();

    float ent = 0.f;
    for (int c = tid; c < NV; c += 256) {
        const float a = sums[c] / msum;
        ent += a * logf(a + 1e-7f);
    }
    red[tid] = ent;
    __syncthreads();
    for (int s = 128; s > 0; s >>= 1) {
        if (tid < s) red[tid] += red[tid + s];
        __syncthreads();
    }
    if (tid == 0) perp[0] = expf(-red[0]);
}

// ---------------------------------------------------------------------------
extern "C" void kernel_launch(void* const* d_in, const int* in_sizes, int n_in,
                              void* d_out, int out_size, void* d_ws, size_t ws_size,
                              hipStream_t stream) {
    const float* x    = (const float*)d_in[0];
    const float* mask = (const float*)d_in[1];
    const float* W    = (const float*)d_in[2];
    const float* cb   = (const float*)d_in[3];

    float* out    = (float*)d_out;
    float* soft   = out + SOFT_OFF;
    float* perp   = out + PERP_OFF;
    float* gumbel = out + GUM_OFF;
    float* sums   = (float*)d_ws;

    hipMemsetAsync(d_ws, 0, NV * sizeof(float), stream);

    k_gemm<<<dim3(NV / BN, NTOK / BM), 256, 0, stream>>>(x, W, mask, soft);
    k_token<<<NTOK / 4, 256, 0, stream>>>(soft, gumbel, out, cb);
    k_colsum<<<dim3(2, 64), 256, 0, stream>>>(soft, mask, sums);
    k_perp<<<1, 256, 0, stream>>>(sums, mask, perp);
}

// Round 2
// 423.890 us; speedup vs baseline: 1.7433x; 1.7433x over previous
//
#include <hip/hip_runtime.h>
#include <math.h>

#define DIM   1024
#define NV    512
#define VD    256
#define NTOK  32768

// Output layout (floats): out | soft | perp | gumbel
#define SOFT_OFF  8388608u    // 32768*256
#define PERP_OFF  25165824u   // + 32768*512
#define GUM_OFF   25165825u   // + 1  (odd -> only 4B aligned!)

#define LO_SCALE      4096.0f
#define INV_LO_SCALE  (1.0f / 4096.0f)

typedef __attribute__((ext_vector_type(8)))  _Float16 half8;
typedef __attribute__((ext_vector_type(4)))  _Float16 half4;
typedef __attribute__((ext_vector_type(16))) float    float16v;

// d_ws layout: Whi (512*1024 f16 = 1MB) | Wlo (1MB) | sums (512 f32)
#define WLO_ELEM_OFF  (NV * DIM)
#define SUMS_BYTE_OFF (2u * NV * DIM * 2u)

// ---------------------------------------------------------------------------
// K0: split W (fp32) into f16 hi plane + scaled f16 lo plane.
//     w = whi + wlo/4096 with |error| ~ 2^-24 relative.
// ---------------------------------------------------------------------------
__global__ __launch_bounds__(256) void k_wsplit(const float* __restrict__ W,
                                                _Float16* __restrict__ whi,
                                                _Float16* __restrict__ wlo) {
    const int i = (blockIdx.x * 256 + threadIdx.x) * 4;
    float4 w = *(const float4*)(W + i);
    _Float16 h0 = (_Float16)w.x, h1 = (_Float16)w.y, h2 = (_Float16)w.z, h3 = (_Float16)w.w;
    _Float16 l0 = (_Float16)((w.x - (float)h0) * LO_SCALE);
    _Float16 l1 = (_Float16)((w.y - (float)h1) * LO_SCALE);
    _Float16 l2 = (_Float16)((w.z - (float)h2) * LO_SCALE);
    _Float16 l3 = (_Float16)((w.w - (float)h3) * LO_SCALE);
    *(half4*)(whi + i) = (half4){h0, h1, h2, h3};
    *(half4*)(wlo + i) = (half4){l0, l1, l2, l3};
}

// ---------------------------------------------------------------------------
// K1: logits = x @ W^T via split-precision f16 MFMA (32x32x16), 3 passes:
//     acc_main += ahi*bhi ; acc_cross += ahi*blo + alo*bhi ;
//     logit = acc_main + acc_cross/4096  (then zero col0, * mask).
// Block: 128x128 C-tile, BK=32, 256 threads = 4 waves in 2x2; each wave
// 64x64 = 2x2 tiles of 32x32. x converted to hi/lo f16 during LDS staging.
// ---------------------------------------------------------------------------
#define BM 128
#define BN 128
#define BK 32
#define LSTR 40   // f16 elems per LDS row (pad 32 -> 40 to break bank stride)

__global__ __launch_bounds__(256, 2) void k_gemm_mfma(
        const float* __restrict__ x,
        const _Float16* __restrict__ whi,
        const _Float16* __restrict__ wlo,
        const float* __restrict__ mask,
        float* __restrict__ logits) {
    __shared__ _Float16 sAh[BM * LSTR];
    __shared__ _Float16 sAl[BM * LSTR];
    __shared__ _Float16 sBh[BN * LSTR];
    __shared__ _Float16 sBl[BN * LSTR];

    const int tid  = threadIdx.x;
    const int lane = tid & 63;
    const int wave = tid >> 6;
    const int wm = wave >> 1, wn = wave & 1;
    const int m0 = blockIdx.y * BM;
    const int n0 = blockIdx.x * BN;

    // staging assignment: thread t -> row lr (0..127), k-chunk kc (0 or 16)
    const int lr = tid >> 1;
    const int kc = (tid & 1) * 16;

    float16v accM[2][2], accC[2][2];
#pragma unroll
    for (int i = 0; i < 2; ++i)
#pragma unroll
        for (int j = 0; j < 2; ++j) {
            accM[i][j] = (float16v)(0.0f);
            accC[i][j] = (float16v)(0.0f);
        }

    const float*    aptr = x   + (size_t)(m0 + lr) * DIM + kc;
    const _Float16* bhp  = whi + (size_t)(n0 + lr) * DIM + kc;
    const _Float16* blp  = wlo + (size_t)(n0 + lr) * DIM + kc;

    const int lm = lane & 31;   // row/col within a 32x32 tile (operand side)
    const int lk = (lane >> 5) * 8;

    for (int k0 = 0; k0 < DIM; k0 += BK) {
        // global loads issued before barrier (overlap with prior compute)
        float4 a0 = *(const float4*)(aptr + k0);
        float4 a1 = *(const float4*)(aptr + k0 + 4);
        float4 a2 = *(const float4*)(aptr + k0 + 8);
        float4 a3 = *(const float4*)(aptr + k0 + 12);
        uint4 bh0 = *(const uint4*)(bhp + k0);
        uint4 bh1 = *(const uint4*)(bhp + k0 + 8);
        uint4 bl0 = *(const uint4*)(blp + k0);
        uint4 bl1 = *(const uint4*)(blp + k0 + 8);

        __syncthreads();   // previous iteration's frag reads done

        float fa[16] = {a0.x, a0.y, a0.z, a0.w, a1.x, a1.y, a1.z, a1.w,
                        a2.x, a2.y, a2.z, a2.w, a3.x, a3.y, a3.z, a3.w};
        _Float16 h[16], l[16];
#pragma unroll
        for (int j = 0; j < 16; ++j) {
            h[j] = (_Float16)fa[j];
            l[j] = (_Float16)((fa[j] - (float)h[j]) * LO_SCALE);
        }
        const int sbase = lr * LSTR + kc;
        *(half8*)&sAh[sbase]     = (half8){h[0], h[1], h[2], h[3], h[4], h[5], h[6], h[7]};
        *(half8*)&sAh[sbase + 8] = (half8){h[8], h[9], h[10], h[11], h[12], h[13], h[14], h[15]};
        *(half8*)&sAl[sbase]     = (half8){l[0], l[1], l[2], l[3], l[4], l[5], l[6], l[7]};
        *(half8*)&sAl[sbase + 8] = (half8){l[8], l[9], l[10], l[11], l[12], l[13], l[14], l[15]};
        *(uint4*)&sBh[sbase]     = bh0;
        *(uint4*)&sBh[sbase + 8] = bh1;
        *(uint4*)&sBl[sbase]     = bl0;
        *(uint4*)&sBl[sbase + 8] = bl1;

        __syncthreads();

#pragma unroll
        for (int hh = 0; hh < 2; ++hh) {   // two K=16 sub-steps of BK=32
            const int koff = hh * 16 + lk;
            half8 ah[2], al[2], bh[2], bl[2];
#pragma unroll
            for (int t = 0; t < 2; ++t) {
                const int arow = wm * 64 + t * 32 + lm;
                ah[t] = *(half8*)&sAh[arow * LSTR + koff];
                al[t] = *(half8*)&sAl[arow * LSTR + koff];
                const int brow = wn * 64 + t * 32 + lm;
                bh[t] = *(half8*)&sBh[brow * LSTR + koff];
                bl[t] = *(half8*)&sBl[brow * LSTR + koff];
            }
#pragma unroll
            for (int ti = 0; ti < 2; ++ti)
#pragma unroll
                for (int tj = 0; tj < 2; ++tj) {
                    accM[ti][tj] = __builtin_amdgcn_mfma_f32_32x32x16_f16(ah[ti], bh[tj], accM[ti][tj], 0, 0, 0);
                    accC[ti][tj] = __builtin_amdgcn_mfma_f32_32x32x16_f16(ah[ti], bl[tj], accC[ti][tj], 0, 0, 0);
                    accC[ti][tj] = __builtin_amdgcn_mfma_f32_32x32x16_f16(al[ti], bh[tj], accC[ti][tj], 0, 0, 0);
                }
        }
    }

    // epilogue: recombine, zero col 0, * mask, store
    const int lq = lane >> 5;
#pragma unroll
    for (int ti = 0; ti < 2; ++ti)
#pragma unroll
        for (int tj = 0; tj < 2; ++tj) {
            const int colbase = n0 + wn * 64 + tj * 32 + lm;
#pragma unroll
            for (int r = 0; r < 16; ++r) {
                const int row = wm * 64 + ti * 32 + (r & 3) + 8 * (r >> 2) + 4 * lq;
                const int m = m0 + row;
                float v = accM[ti][tj][r] + accC[ti][tj][r] * INV_LO_SCALE;
                v *= mask[m];
                if (colbase == 0) v = 0.0f;
                logits[(size_t)m * NV + colbase] = v;
            }
        }
}

// ---------------------------------------------------------------------------
// K2: per-token epilogue. One 64-lane wave per token (4 waves / block).
// ---------------------------------------------------------------------------
__global__ __launch_bounds__(256) void k_token(float* __restrict__ soft,
                                               float* __restrict__ gumbel,
                                               float* __restrict__ outp,
                                               const float* __restrict__ codebook) {
    const int lane = threadIdx.x & 63;
    const int wave = threadIdx.x >> 6;
    const int t = blockIdx.x * 4 + wave;

    float* row = soft + (size_t)t * NV;
    float4 u0 = *(const float4*)(row + lane * 4);
    float4 u1 = *(const float4*)(row + 256 + lane * 4);
    float v[8] = {u0.x, u0.y, u0.z, u0.w, u1.x, u1.y, u1.z, u1.w};
    int idx[8];
#pragma unroll
    for (int j = 0; j < 4; ++j) { idx[j] = lane * 4 + j; idx[4 + j] = 256 + lane * 4 + j; }

    float bmax = v[0]; int bidx = idx[0];
#pragma unroll
    for (int j = 1; j < 8; ++j)
        if (v[j] > bmax) { bmax = v[j]; bidx = idx[j]; }
#pragma unroll
    for (int off = 32; off > 0; off >>= 1) {
        float om = __shfl_xor(bmax, off, 64);
        int   oi = __shfl_xor(bidx, off, 64);
        if (om > bmax || (om == bmax && oi < bidx)) { bmax = om; bidx = oi; }
    }
    const float mval = bmax;
    const int k = bidx;

    float e[8]; float s = 0.f;
#pragma unroll
    for (int j = 0; j < 8; ++j) { e[j] = __expf(v[j] - mval); s += e[j]; }
#pragma unroll
    for (int off = 32; off > 0; off >>= 1) s += __shfl_xor(s, off, 64);
    const float inv = 1.f / s;
    float4 w0 = {e[0] * inv, e[1] * inv, e[2] * inv, e[3] * inv};
    float4 w1 = {e[4] * inv, e[5] * inv, e[6] * inv, e[7] * inv};
    *(float4*)(row + lane * 4) = w0;
    *(float4*)(row + 256 + lane * 4) = w1;

    float* grow = gumbel + (size_t)t * NV;
#pragma unroll
    for (int j = 0; j < 8; ++j) {
        const int col = j * 64 + lane;
        grow[col] = (col == k) ? 1.f : 0.f;
    }

    float4 cbv;
    if (k == 0) {
        cbv.x = cbv.y = cbv.z = cbv.w = 0.f;
    } else {
        cbv = *(const float4*)(codebook + (size_t)k * VD + lane * 4);
    }
    *(float4*)(outp + (size_t)t * VD + lane * 4) = cbv;
}

// ---------------------------------------------------------------------------
// K3: masked column sums of soft_probs -> sums[0..512)
// ---------------------------------------------------------------------------
__global__ __launch_bounds__(256) void k_colsum(const float* __restrict__ soft,
                                                const float* __restrict__ mask,
                                                float* __restrict__ sums) {
    const int c = blockIdx.x * 256 + threadIdx.x;
    const int r0 = blockIdx.y * 128;
    float acc = 0.f;
    for (int r = r0; r < r0 + 128; ++r)
        acc = fmaf(soft[(size_t)r * NV + c], mask[r], acc);
    atomicAdd(&sums[c], acc);
}

// ---------------------------------------------------------------------------
// K4: perplexity
// ---------------------------------------------------------------------------
__global__ __launch_bounds__(256) void k_perp(const float* __restrict__ sums,
                                              const float* __restrict__ mask,
                                              float* __restrict__ perp) {
    __shared__ float red[256];
    const int tid = threadIdx.x;
    float ms = 0.f;
    for (int r = tid; r < NTOK; r += 256) ms += mask[r];
    red[tid] = ms;
    __syncthreads();
    for (int s = 128; s > 0; s >>= 1) {
        if (tid < s) red[tid] += red[tid + s];
        __syncthreads();
    }
    const float msum = red[0];
    __syncthreads();

    float ent = 0.f;
    for (int c = tid; c < NV; c += 256) {
        const float a = sums[c] / msum;
        ent += a * logf(a + 1e-7f);
    }
    red[tid] = ent;
    __syncthreads();
    for (int s = 128; s > 0; s >>= 1) {
        if (tid < s) red[tid] += red[tid + s];
        __syncthreads();
    }
    if (tid == 0) perp[0] = expf(-red[0]);
}

// ---------------------------------------------------------------------------
extern "C" void kernel_launch(void* const* d_in, const int* in_sizes, int n_in,
                              void* d_out, int out_size, void* d_ws, size_t ws_size,
                              hipStream_t stream) {
    const float* x    = (const float*)d_in[0];
    const float* mask = (const float*)d_in[1];
    const float* W    = (const float*)d_in[2];
    const float* cb   = (const float*)d_in[3];

    float* out    = (float*)d_out;
    float* soft   = out + SOFT_OFF;
    float* perp   = out + PERP_OFF;
    float* gumbel = out + GUM_OFF;

    _Float16* whi = (_Float16*)d_ws;
    _Float16* wlo = whi + WLO_ELEM_OFF;
    float* sums   = (float*)((char*)d_ws + SUMS_BYTE_OFF);

    hipMemsetAsync(sums, 0, NV * sizeof(float), stream);

    k_wsplit<<<NV * DIM / (256 * 4), 256, 0, stream>>>(W, whi, wlo);
    k_gemm_mfma<<<dim3(NV / BN, NTOK / BM), 256, 0, stream>>>(x, whi, wlo, mask, soft);
    k_token<<<NTOK / 4, 256, 0, stream>>>(soft, gumbel, out, cb);
    k_colsum<<<dim3(2, 256), 256, 0, stream>>>(soft, mask, sums);
    k_perp<<<1, 256, 0, stream>>>(sums, mask, perp);
}

// Round 3
// 401.471 us; speedup vs baseline: 1.8407x; 1.0558x over previous
//
#include <hip/hip_runtime.h>
#include <math.h>

#define DIM   1024
#define NV    512
#define VD    256
#define NTOK  32768

// Output layout (floats): out | soft | perp | gumbel
#define SOFT_OFF  8388608u    // 32768*256
#define PERP_OFF  25165824u   // + 32768*512
#define GUM_OFF   25165825u   // + 1  (odd -> only 4B aligned!)

#define LO_SCALE      4096.0f
#define INV_LO_SCALE  (1.0f / 4096.0f)

typedef __attribute__((ext_vector_type(8)))  _Float16 half8;
typedef __attribute__((ext_vector_type(4)))  _Float16 half4;
typedef __attribute__((ext_vector_type(16))) float    float16v;

// d_ws layout: Whi (1MB f16) | Wlo (1MB f16) | sums (512 col sums + 1 mask sum)
#define WLO_ELEM_OFF  (NV * DIM)
#define SUMS_BYTE_OFF (2u * NV * DIM * 2u)

// ---------------------------------------------------------------------------
// K0: split W (fp32) into f16 hi plane + scaled f16 lo plane.
// ---------------------------------------------------------------------------
__global__ __launch_bounds__(256) void k_wsplit(const float* __restrict__ W,
                                                _Float16* __restrict__ whi,
                                                _Float16* __restrict__ wlo) {
    const int i = (blockIdx.x * 256 + threadIdx.x) * 4;
    float4 w = *(const float4*)(W + i);
    _Float16 h0 = (_Float16)w.x, h1 = (_Float16)w.y, h2 = (_Float16)w.z, h3 = (_Float16)w.w;
    _Float16 l0 = (_Float16)((w.x - (float)h0) * LO_SCALE);
    _Float16 l1 = (_Float16)((w.y - (float)h1) * LO_SCALE);
    _Float16 l2 = (_Float16)((w.z - (float)h2) * LO_SCALE);
    _Float16 l3 = (_Float16)((w.w - (float)h3) * LO_SCALE);
    *(half4*)(whi + i) = (half4){h0, h1, h2, h3};
    *(half4*)(wlo + i) = (half4){l0, l1, l2, l3};
}

// ---------------------------------------------------------------------------
// K1: logits = x @ W^T via split-precision f16 MFMA (32x32x16), 3 passes.
// (unchanged from R2 — isolating the epilogue change this round)
// ---------------------------------------------------------------------------
#define BM 128
#define BN 128
#define BK 32
#define LSTR 40

__global__ __launch_bounds__(256, 2) void k_gemm_mfma(
        const float* __restrict__ x,
        const _Float16* __restrict__ whi,
        const _Float16* __restrict__ wlo,
        const float* __restrict__ mask,
        float* __restrict__ logits) {
    __shared__ _Float16 sAh[BM * LSTR];
    __shared__ _Float16 sAl[BM * LSTR];
    __shared__ _Float16 sBh[BN * LSTR];
    __shared__ _Float16 sBl[BN * LSTR];

    const int tid  = threadIdx.x;
    const int lane = tid & 63;
    const int wave = tid >> 6;
    const int wm = wave >> 1, wn = wave & 1;
    const int m0 = blockIdx.y * BM;
    const int n0 = blockIdx.x * BN;

    const int lr = tid >> 1;
    const int kc = (tid & 1) * 16;

    float16v accM[2][2], accC[2][2];
#pragma unroll
    for (int i = 0; i < 2; ++i)
#pragma unroll
        for (int j = 0; j < 2; ++j) {
            accM[i][j] = (float16v)(0.0f);
            accC[i][j] = (float16v)(0.0f);
        }

    const float*    aptr = x   + (size_t)(m0 + lr) * DIM + kc;
    const _Float16* bhp  = whi + (size_t)(n0 + lr) * DIM + kc;
    const _Float16* blp  = wlo + (size_t)(n0 + lr) * DIM + kc;

    const int lm = lane & 31;
    const int lk = (lane >> 5) * 8;

    for (int k0 = 0; k0 < DIM; k0 += BK) {
        float4 a0 = *(const float4*)(aptr + k0);
        float4 a1 = *(const float4*)(aptr + k0 + 4);
        float4 a2 = *(const float4*)(aptr + k0 + 8);
        float4 a3 = *(const float4*)(aptr + k0 + 12);
        uint4 bh0 = *(const uint4*)(bhp + k0);
        uint4 bh1 = *(const uint4*)(bhp + k0 + 8);
        uint4 bl0 = *(const uint4*)(blp + k0);
        uint4 bl1 = *(const uint4*)(blp + k0 + 8);

        __syncthreads();

        float fa[16] = {a0.x, a0.y, a0.z, a0.w, a1.x, a1.y, a1.z, a1.w,
                        a2.x, a2.y, a2.z, a2.w, a3.x, a3.y, a3.z, a3.w};
        _Float16 h[16], l[16];
#pragma unroll
        for (int j = 0; j < 16; ++j) {
            h[j] = (_Float16)fa[j];
            l[j] = (_Float16)((fa[j] - (float)h[j]) * LO_SCALE);
        }
        const int sbase = lr * LSTR + kc;
        *(half8*)&sAh[sbase]     = (half8){h[0], h[1], h[2], h[3], h[4], h[5], h[6], h[7]};
        *(half8*)&sAh[sbase + 8] = (half8){h[8], h[9], h[10], h[11], h[12], h[13], h[14], h[15]};
        *(half8*)&sAl[sbase]     = (half8){l[0], l[1], l[2], l[3], l[4], l[5], l[6], l[7]};
        *(half8*)&sAl[sbase + 8] = (half8){l[8], l[9], l[10], l[11], l[12], l[13], l[14], l[15]};
        *(uint4*)&sBh[sbase]     = bh0;
        *(uint4*)&sBh[sbase + 8] = bh1;
        *(uint4*)&sBl[sbase]     = bl0;
        *(uint4*)&sBl[sbase + 8] = bl1;

        __syncthreads();

#pragma unroll
        for (int hh = 0; hh < 2; ++hh) {
            const int koff = hh * 16 + lk;
            half8 ah[2], al[2], bh[2], bl[2];
#pragma unroll
            for (int t = 0; t < 2; ++t) {
                const int arow = wm * 64 + t * 32 + lm;
                ah[t] = *(half8*)&sAh[arow * LSTR + koff];
                al[t] = *(half8*)&sAl[arow * LSTR + koff];
                const int brow = wn * 64 + t * 32 + lm;
                bh[t] = *(half8*)&sBh[brow * LSTR + koff];
                bl[t] = *(half8*)&sBl[brow * LSTR + koff];
            }
#pragma unroll
            for (int ti = 0; ti < 2; ++ti)
#pragma unroll
                for (int tj = 0; tj < 2; ++tj) {
                    accM[ti][tj] = __builtin_amdgcn_mfma_f32_32x32x16_f16(ah[ti], bh[tj], accM[ti][tj], 0, 0, 0);
                    accC[ti][tj] = __builtin_amdgcn_mfma_f32_32x32x16_f16(ah[ti], bl[tj], accC[ti][tj], 0, 0, 0);
                    accC[ti][tj] = __builtin_amdgcn_mfma_f32_32x32x16_f16(al[ti], bh[tj], accC[ti][tj], 0, 0, 0);
                }
        }
    }

    const int lq = lane >> 5;
#pragma unroll
    for (int ti = 0; ti < 2; ++ti)
#pragma unroll
        for (int tj = 0; tj < 2; ++tj) {
            const int colbase = n0 + wn * 64 + tj * 32 + lm;
#pragma unroll
            for (int r = 0; r < 16; ++r) {
                const int row = wm * 64 + ti * 32 + (r & 3) + 8 * (r >> 2) + 4 * lq;
                const int m = m0 + row;
                float v = accM[ti][tj][r] + accC[ti][tj][r] * INV_LO_SCALE;
                v *= mask[m];
                if (colbase == 0) v = 0.0f;
                logits[(size_t)m * NV + colbase] = v;
            }
        }
}

// ---------------------------------------------------------------------------
// K2: fused per-token epilogue. One wave handles 8 tokens (interleaved chains
// for ILP/MLP); also accumulates masked column sums (block LDS -> global
// atomics) and the mask sum -> sums[512]. Replaces old k_token + k_colsum.
// ---------------------------------------------------------------------------
#define TPW 8   // tokens per wave; block = 4 waves = 32 tokens

__global__ __launch_bounds__(256) void k_token(float* __restrict__ soft,
                                               float* __restrict__ gumbel,
                                               float* __restrict__ outp,
                                               const float* __restrict__ codebook,
                                               const float* __restrict__ mask,
                                               float* __restrict__ sums) {
    __shared__ float scol[NV];
    const int tid  = threadIdx.x;
    const int lane = tid & 63;
    const int wave = tid >> 6;
    const int tblk = blockIdx.x * 32;
    const int t0   = tblk + wave * TPW;

    scol[tid] = 0.f;
    scol[tid + 256] = 0.f;

    // 16 independent loads in flight
    float4 u0[TPW], u1[TPW];
#pragma unroll
    for (int t = 0; t < TPW; ++t) {
        const float* row = soft + (size_t)(t0 + t) * NV;
        u0[t] = *(const float4*)(row + lane * 4);
        u1[t] = *(const float4*)(row + 256 + lane * 4);
    }
    __syncthreads();   // scol zeroed before any atomic add

    // per-lane argmax (lowest index on ties: strict >, ascending idx order)
    float bm[TPW]; int bi[TPW];
#pragma unroll
    for (int t = 0; t < TPW; ++t) {
        float v[8] = {u0[t].x, u0[t].y, u0[t].z, u0[t].w,
                      u1[t].x, u1[t].y, u1[t].z, u1[t].w};
        float m = v[0]; int ix = lane * 4;
#pragma unroll
        for (int j = 1; j < 8; ++j) {
            const int col = (j < 4) ? (lane * 4 + j) : (256 + lane * 4 + (j - 4));
            if (v[j] > m) { m = v[j]; ix = col; }
        }
        bm[t] = m; bi[t] = ix;
    }
    // wave butterfly, 8 tokens interleaved per stage
#pragma unroll
    for (int off = 32; off > 0; off >>= 1) {
#pragma unroll
        for (int t = 0; t < TPW; ++t) {
            float om = __shfl_xor(bm[t], off, 64);
            int   oi = __shfl_xor(bi[t], off, 64);
            if (om > bm[t] || (om == bm[t] && oi < bi[t])) { bm[t] = om; bi[t] = oi; }
        }
    }

    // softmax: exp in place, interleaved sum butterflies
    float s[TPW];
#pragma unroll
    for (int t = 0; t < TPW; ++t) {
        u0[t].x = __expf(u0[t].x - bm[t]); u0[t].y = __expf(u0[t].y - bm[t]);
        u0[t].z = __expf(u0[t].z - bm[t]); u0[t].w = __expf(u0[t].w - bm[t]);
        u1[t].x = __expf(u1[t].x - bm[t]); u1[t].y = __expf(u1[t].y - bm[t]);
        u1[t].z = __expf(u1[t].z - bm[t]); u1[t].w = __expf(u1[t].w - bm[t]);
        s[t] = u0[t].x + u0[t].y + u0[t].z + u0[t].w
             + u1[t].x + u1[t].y + u1[t].z + u1[t].w;
    }
#pragma unroll
    for (int off = 32; off > 0; off >>= 1)
#pragma unroll
        for (int t = 0; t < TPW; ++t) s[t] += __shfl_xor(s[t], off, 64);

    float ca0[4] = {0.f, 0.f, 0.f, 0.f};
    float ca1[4] = {0.f, 0.f, 0.f, 0.f};

#pragma unroll
    for (int t = 0; t < TPW; ++t) {
        const float inv = 1.f / s[t];
        const int tok = t0 + t;
        const float mk = mask[tok];
        u0[t].x *= inv; u0[t].y *= inv; u0[t].z *= inv; u0[t].w *= inv;
        u1[t].x *= inv; u1[t].y *= inv; u1[t].z *= inv; u1[t].w *= inv;

        float* row = soft + (size_t)tok * NV;
        *(float4*)(row + lane * 4) = u0[t];
        *(float4*)(row + 256 + lane * 4) = u1[t];

        ca0[0] += u0[t].x * mk; ca0[1] += u0[t].y * mk;
        ca0[2] += u0[t].z * mk; ca0[3] += u0[t].w * mk;
        ca1[0] += u1[t].x * mk; ca1[1] += u1[t].y * mk;
        ca1[2] += u1[t].z * mk; ca1[3] += u1[t].w * mk;

        const int k = bi[t];
        float* grow = gumbel + (size_t)tok * NV;
#pragma unroll
        for (int j = 0; j < 8; ++j) {
            const int col = j * 64 + lane;
            grow[col] = (col == k) ? 1.f : 0.f;
        }

        float4 cbv;
        if (k == 0) {
            cbv.x = cbv.y = cbv.z = cbv.w = 0.f;
        } else {
            cbv = *(const float4*)(codebook + (size_t)k * VD + lane * 4);
        }
        *(float4*)(outp + (size_t)tok * VD + lane * 4) = cbv;
    }

    // block-level column accumulation (LDS), then one global atomic per column
#pragma unroll
    for (int j = 0; j < 4; ++j) {
        atomicAdd(&scol[lane * 4 + j], ca0[j]);
        atomicAdd(&scol[256 + lane * 4 + j], ca1[j]);
    }
    __syncthreads();
    atomicAdd(&sums[tid], scol[tid]);
    atomicAdd(&sums[tid + 256], scol[tid + 256]);

    // mask sum for this block's 32 tokens (wave 0 only)
    if (wave == 0) {
        float mv = (lane < 32) ? mask[tblk + lane] : 0.f;
#pragma unroll
        for (int off = 32; off > 0; off >>= 1) mv += __shfl_xor(mv, off, 64);
        if (lane == 0) atomicAdd(&sums[NV], mv);
    }
}

// ---------------------------------------------------------------------------
// K3: perplexity from 513 accumulated floats (no 128KB mask re-read)
// ---------------------------------------------------------------------------
__global__ __launch_bounds__(256) void k_perp(const float* __restrict__ sums,
                                              float* __restrict__ perp) {
    __shared__ float red[256];
    const int tid = threadIdx.x;
    const float msum = sums[NV];
    float ent = 0.f;
    for (int c = tid; c < NV; c += 256) {
        const float a = sums[c] / msum;
        ent += a * logf(a + 1e-7f);
    }
    red[tid] = ent;
    __syncthreads();
    for (int s = 128; s > 0; s >>= 1) {
        if (tid < s) red[tid] += red[tid + s];
        __syncthreads();
    }
    if (tid == 0) perp[0] = expf(-red[0]);
}

// ---------------------------------------------------------------------------
extern "C" void kernel_launch(void* const* d_in, const int* in_sizes, int n_in,
                              void* d_out, int out_size, void* d_ws, size_t ws_size,
                              hipStream_t stream) {
    const float* x    = (const float*)d_in[0];
    const float* mask = (const float*)d_in[1];
    const float* W    = (const float*)d_in[2];
    const float* cb   = (const float*)d_in[3];

    float* out    = (float*)d_out;
    float* soft   = out + SOFT_OFF;
    float* perp   = out + PERP_OFF;
    float* gumbel = out + GUM_OFF;

    _Float16* whi = (_Float16*)d_ws;
    _Float16* wlo = whi + WLO_ELEM_OFF;
    float* sums   = (float*)((char*)d_ws + SUMS_BYTE_OFF);

    hipMemsetAsync(sums, 0, (NV + 1) * sizeof(float), stream);

    k_wsplit<<<NV * DIM / (256 * 4), 256, 0, stream>>>(W, whi, wlo);
    k_gemm_mfma<<<dim3(NV / BN, NTOK / BM), 256, 0, stream>>>(x, whi, wlo, mask, soft);
    k_token<<<NTOK / 32, 256, 0, stream>>>(soft, gumbel, out, cb, mask, sums);
    k_perp<<<1, 256, 0, stream>>>(sums, perp);
}